// Round 6
// baseline (130.738 us; speedup 1.0000x reference)
//
#include <hip/hip_runtime.h>
#include <hip/hip_bf16.h>
#include <hip/hip_cooperative_groups.h>

namespace cg = cooperative_groups;

typedef unsigned short u16;
typedef unsigned int u32;
typedef __bf16 bf16x8_t __attribute__((ext_vector_type(8)));
typedef float f32x4_t __attribute__((ext_vector_type(4)));

constexpr int Bb = 4;
constexpr int Tt = 4096;
constexpr int Dd = 64;
constexpr float QSCALE = 0.18033688011112042f; // 0.125 * log2(e), folded into q

__device__ __forceinline__ u16 f2bf(float f) { // RNE
  unsigned int u = __builtin_bit_cast(unsigned int, f);
  return (u16)((u + 0x7fffu + ((u >> 16) & 1u)) >> 16);
}
__device__ __forceinline__ u32 pk2(float a, float b) { // RNE pack
  return (u32)f2bf(a) | ((u32)f2bf(b) << 16);
}
__device__ __forceinline__ u32 pkt(float a, float b) { // truncation pack (3 inst)
  const u32 ua = __builtin_bit_cast(u32, a);
  const u32 ub = __builtin_bit_cast(u32, b);
  return (ua >> 16) | (ub & 0xFFFF0000u);
}
__device__ __forceinline__ bf16x8_t ld16(const u16* p) {
  int4 v = *(const int4*)p;
  return __builtin_bit_cast(bf16x8_t, v);
}
__device__ __forceinline__ f32x4_t mfma16(bf16x8_t a, bf16x8_t b, f32x4_t c) {
  return __builtin_amdgcn_mfma_f32_16x16x32_bf16(a, b, c, 0, 0, 0);
}

// ================= fused: proj (16-wave restructure) + grid.sync + flash v10 (verbatim) ==========
// Proj phase: block blk stages rows blk*64.. of x plus Wk/Wq/Wv (4 float4/thread), then wave-groups
// mg=0/1/2 compute m=k/q/v GEMMs in parallel (one barrier, not 3 serial m-iterations).
// Flash phase: v10 exactly — balanced q-tile pair (i, 127-i), proportional wave split, in-LDS merge.
// One dispatch total: kills 2 launch gaps and makes the kernel visible to rocprof top-5.
__global__ __launch_bounds__(1024, 4) void HeadV1_fused(
    const float* __restrict__ x, const float* __restrict__ Wk,
    const float* __restrict__ Wq, const float* __restrict__ Wv,
    u16* qS, u16* kS, u16* vS, float* outg)
{
  __shared__ __align__(16) char smem[65536];

  const int t    = threadIdx.x;
  const int w    = t >> 6;        // 0..15
  const int lane = t & 63;
  const int l15  = lane & 15;
  const int quad = lane >> 4;

  // ---------------- phase 1: proj ----------------
  {
    u16 (*xl)[72]    = (u16 (*)[72])smem;                 //  9216 B
    u16 (*Wl)[64][72] = (u16 (*)[64][72])(smem + 9216);   // 27648 B
    u16 (*yl)[64][72] = (u16 (*)[64][72])(smem + 36864);  // 27648 B (total 64512)

    const int blk = blockIdx.x;
    const int r0 = blk * 64;
    const int b  = blk >> 6;
    const int kt = blk & 63;
    const long tilebase = ((long)(b * 64 + kt)) * 4096;

    { // staging: 1024 threads x 1 float4 per tile
      const float* srcs[4] = {x + (long)r0 * 64, Wk, Wq, Wv};
      u16* dstl[4] = {&xl[0][0], &Wl[0][0][0], &Wl[1][0][0], &Wl[2][0][0]};
      const int row = t >> 4, c4 = t & 15;
      #pragma unroll
      for (int mm = 0; mm < 4; mm++) {
        float4 v = ((const float4*)(srcs[mm] + row * 64))[c4];
        uint2 pk;
        pk.x = pk2(v.x, v.y);
        pk.y = pk2(v.z, v.w);
        *(uint2*)(dstl[mm] + row * 72 + c4 * 4) = pk;
      }
    }
    __syncthreads();

    const int mg = w >> 2;       // wave group: 0=k 1=q 2=v 3=idle
    const int wl = w & 3;        // wave-in-group (role of old proj's w)
    if (mg < 3) {
      bf16x8_t xf[2];
      #pragma unroll
      for (int kh = 0; kh < 2; kh++)
        xf[kh] = ld16(&xl[wl * 16 + l15][kh * 32 + quad * 8]);

      float vals[4][4];
      #pragma unroll
      for (int g = 0; g < 4; g++) {
        f32x4_t acc = {0.f, 0.f, 0.f, 0.f};
        #pragma unroll
        for (int kh = 0; kh < 2; kh++) {
          bf16x8_t wf = ld16(&Wl[mg][g * 16 + l15][kh * 32 + quad * 8]);
          acc = mfma16(xf[kh], wf, acc);
        }
        #pragma unroll
        for (int r = 0; r < 4; r++)
          vals[g][r] = (mg == 1) ? acc[r] * QSCALE : acc[r];
      }
      #pragma unroll
      for (int g = 0; g < 4; g++)
        #pragma unroll
        for (int r = 0; r < 4; r++)
          yl[mg][wl * 16 + quad * 4 + r][g * 16 + l15] = f2bf(vals[g][r]);
    }
    __syncthreads();

    if (mg < 3) {
      u16* dsts[3];
      dsts[0] = kS + tilebase; dsts[1] = qS + tilebase; dsts[2] = vS + tilebase;
      if (mg < 2) {
        #pragma unroll
        for (int kk = 0; kk < 2; kk++) {
          bf16x8_t f = ld16(&yl[mg][wl * 16 + l15][kk * 32 + quad * 8]);
          *(int4*)(dsts[mg] + (wl * 2 + kk) * 512 + lane * 8) = __builtin_bit_cast(int4, f);
        }
      } else {
        #pragma unroll
        for (int kk = 0; kk < 2; kk++) {
          u16 tmp[8];
          #pragma unroll
          for (int jj = 0; jj < 8; jj++)
            tmp[jj] = yl[2][kk * 32 + quad * 8 + jj][wl * 16 + l15];
          *(int4*)(dsts[2] + (kk * 4 + wl) * 512 + lane * 8) = *(const int4*)tmp;
        }
      }
    }
  }

  cg::this_grid().sync();   // device-scope: qS/kS/vS visible to all XCDs

  // ---------------- phase 2: flash v10 (verbatim, smem overlay) ----------------
  {
    u16  (*pT)[2 * 36 * 32]= (u16 (*)[2*36*32])smem;              // [16][32][36]x2... layout below
    // v10 layout: pT [16][32][36] u16 @0 (36864); chk [16][16][33] f32 @0; stg [2][32][68] f32 @33792;
    // lst [16][32] f32 @51200.
    u16  (*pT2)[32][36]   = (u16 (*)[32][36])smem;
    float (*chk)[16][33]  = (float (*)[16][33])smem;
    float (*stg)[32][68]  = (float (*)[32][68])(smem + 33792);
    float (*lst)[32]      = (float (*)[32])(smem + 51200);
    (void)pT;

    const int b  = blockIdx.x & 3;
    const int i  = blockIdx.x >> 2;      // 0..63
    const int j1 = i, j2 = 127 - i;
    const int nk1 = (j1 >> 1) + 1;
    const int nk2 = (j2 >> 1) + 1;       // nk1 + nk2 == 65
    int n1 = (16 * nk1 + 32) / 65;       // round(16*nk1/65)
    if (n1 < 1) n1 = 1;
    if (n1 > 15) n1 = 15;

    const bool grp2 = (w >= n1);
    const int j   = grp2 ? j2 : j1;
    const int nk  = grp2 ? nk2 : nk1;
    const int str = grp2 ? (16 - n1) : n1;
    const int off = grp2 ? (w - n1) : w;

    const int qt64 = j >> 1;
    const int ql0  = (j & 1) * 32;
    const int qr0  = j * 32;
    const long base = (long)b * Tt * Dd;

    union { u32 u4[4]; bf16x8_t v; } uo;
    uo.u4[0] = uo.u4[1] = uo.u4[2] = uo.u4[3] = 0x3F803F80u; // bf16 1.0 x8
    const bf16x8_t ones = uo.v;
    const f32x4_t zero4 = {0.f, 0.f, 0.f, 0.f};

    const u16* qtile = qS + ((long)(b * 64 + qt64)) * 4096 + lane * 8;
    bf16x8_t qfrag[2][2];
    #pragma unroll
    for (int ct = 0; ct < 2; ct++)
      #pragma unroll
      for (int kd = 0; kd < 2; kd++)
        qfrag[ct][kd] = ld16(qtile + ((ql0 / 16 + ct) * 2 + kd) * 512);

    f32x4_t O[4][2];   // [dt][ct]
    #pragma unroll
    for (int a = 0; a < 4; a++)
      #pragma unroll
      for (int c = 0; c < 2; c++)
        O[a][c] = zero4;
    f32x4_t Lc[2] = {zero4, zero4};

    for (int kt = off; kt < nk; kt += str) {
      const bool ismask = (kt == nk - 1);
      const int kv0 = kt * 64;
      const u16* ktile = kS + ((long)(b * 64 + kt)) * 4096 + lane * 8;
      const u16* vtile = vS + ((long)(b * 64 + kt)) * 4096 + lane * 8;

      #pragma unroll
      for (int kk = 0; kk < 2; kk++) {     // kv-half phase
        bf16x8_t vf[4];
        #pragma unroll
        for (int dt = 0; dt < 4; dt++)
          vf[dt] = ld16(vtile + (kk * 4 + dt) * 512);

        #pragma unroll
        for (int rtl = 0; rtl < 2; rtl++) {
          const int rt = kk * 2 + rtl;
          bf16x8_t kf0 = ld16(ktile + (rt * 2 + 0) * 512);
          bf16x8_t kf1 = ld16(ktile + (rt * 2 + 1) * 512);
          #pragma unroll
          for (int ct = 0; ct < 2; ct++) {
            f32x4_t acc = zero4;
            acc = mfma16(kf0, qfrag[ct][0], acc);
            acc = mfma16(kf1, qfrag[ct][1], acc);
            if (ismask) {
              const int kvl = kv0 + rt * 16 + quad * 4;
              const int qi  = qr0 + ct * 16 + l15;
              #pragma unroll
              for (int r = 0; r < 4; r++)
                if (kvl + r > qi) acc[r] = -1e30f;   // v_exp -> 0
            }
            const float p0 = __builtin_amdgcn_exp2f(acc[0]);
            const float p1 = __builtin_amdgcn_exp2f(acc[1]);
            const float p2 = __builtin_amdgcn_exp2f(acc[2]);
            const float p3 = __builtin_amdgcn_exp2f(acc[3]);
            uint2 pk;
            pk.x = pkt(p0, p1);
            pk.y = pkt(p2, p3);
            *(uint2*)&pT2[w][ct * 16 + l15][rtl * 16 + quad * 4] = pk;
          }
        }
        #pragma unroll
        for (int ct = 0; ct < 2; ct++) {
          bf16x8_t pf = ld16(&pT2[w][ct * 16 + l15][quad * 8]);
          #pragma unroll
          for (int dt = 0; dt < 4; dt++)
            O[dt][ct] = mfma16(vf[dt], pf, O[dt][ct]);
          Lc[ct] = mfma16(ones, pf, Lc[ct]);
        }
      }
    }

    // ---- 16-wave merge, per-j wave ranges [0,n1) / [n1,16) ----
    if (quad == 0) {
      #pragma unroll
      for (int ct = 0; ct < 2; ct++)
        lst[w][ct * 16 + l15] = Lc[ct][0];
    }
    __syncthreads();  // pT dead past here; chk/stg overlay it

    #pragma unroll
    for (int dt = 0; dt < 4; dt++) {
      #pragma unroll
      for (int ct = 0; ct < 2; ct++)
        #pragma unroll
        for (int r = 0; r < 4; r++)
          chk[w][quad * 4 + r][ct * 16 + l15] = O[dt][ct][r];
      __syncthreads();
      {
        const int jsel = t >> 9, tt = t & 511;
        const int d2 = tt >> 5, q = tt & 31;   // 512 threads = 16 d x 32 q per jsel
        const int lo = jsel ? n1 : 0, hi = jsel ? 16 : n1;
        float s = 0.f;
        for (int w2 = lo; w2 < hi; w2++) s += chk[w2][d2][q];
        stg[jsel][q][dt * 16 + d2] = s;
      }
      __syncthreads();
    }

    { // normalize + coalesced fp32 write: per jsel, 32 q x 64 d (512 thr x 16 B)
      const int jsel = t >> 9, tt = t & 511;
      const int q = tt >> 4, dg = tt & 15;
      const int lo = jsel ? n1 : 0, hi = jsel ? 16 : n1;
      float L = 0.f;
      for (int w2 = lo; w2 < hi; w2++) L += lst[w2][q];
      const float invL = 1.0f / L;
      const int jj = jsel ? j2 : j1;
      float4 v = *(const float4*)&stg[jsel][q][dg * 4];
      v.x *= invL; v.y *= invL; v.z *= invL; v.w *= invL;
      *(float4*)(outg + base + (long)(jj * 32 + q) * 64 + dg * 4) = v;
    }
  }
}

extern "C" void kernel_launch(void* const* d_in, const int* in_sizes, int n_in,
                              void* d_out, int out_size, void* d_ws, size_t ws_size,
                              hipStream_t stream) {
  (void)in_sizes; (void)n_in; (void)out_size; (void)ws_size;
  const float* x  = (const float*)d_in[0];
  const float* Wk = (const float*)d_in[1];
  const float* Wq = (const float*)d_in[2];
  const float* Wv = (const float*)d_in[3];
  float* out = (float*)d_out;
  // workspace: qS 2MB | kS 2MB | vS 2MB (all in MFMA-fragment order)
  u16* qw  = (u16*)d_ws;
  u16* kw  = qw + (size_t)Bb * Tt * Dd;
  u16* vw  = kw + (size_t)Bb * Tt * Dd;

  void* kargs[] = {(void*)&x, (void*)&Wk, (void*)&Wq, (void*)&Wv,
                   (void*)&qw, (void*)&kw, (void*)&vw, (void*)&out};
  hipLaunchCooperativeKernel((void*)HeadV1_fused, dim3(256), dim3(1024),
                             kargs, 0, stream);
}

// Round 7
// 83.781 us; speedup vs baseline: 1.5605x; 1.5605x over previous
//
#include <hip/hip_runtime.h>
#include <hip/hip_bf16.h>

typedef unsigned short u16;
typedef unsigned int u32;
typedef __bf16 bf16x8_t __attribute__((ext_vector_type(8)));
typedef float f32x4_t __attribute__((ext_vector_type(4)));

constexpr int Bb = 4;
constexpr int Tt = 4096;
constexpr int Dd = 64;
constexpr float QSCALE = 0.18033688011112042f; // 0.125 * log2(e), folded into q

__device__ __forceinline__ u16 f2bf(float f) { // RNE
  unsigned int u = __builtin_bit_cast(unsigned int, f);
  return (u16)((u + 0x7fffu + ((u >> 16) & 1u)) >> 16);
}
__device__ __forceinline__ u32 pk2(float a, float b) { // RNE pack
  return (u32)f2bf(a) | ((u32)f2bf(b) << 16);
}
__device__ __forceinline__ u32 pkt(float a, float b) { // truncation pack (3 inst)
  const u32 ua = __builtin_bit_cast(u32, a);
  const u32 ub = __builtin_bit_cast(u32, b);
  return (ua >> 16) | (ub & 0xFFFF0000u);
}
__device__ __forceinline__ bf16x8_t ld16(const u16* p) {
  int4 v = *(const int4*)p;
  return __builtin_bit_cast(bf16x8_t, v);
}
__device__ __forceinline__ f32x4_t mfma16(bf16x8_t a, bf16x8_t b, f32x4_t c) {
  return __builtin_amdgcn_mfma_f32_16x16x32_bf16(a, b, c, 0, 0, 0);
}

// ---------------- proj v4 (R17, verified): LDS-staged x and W, fragment-order outputs ----------------
//   qS/kS tile (b*64+t): frag(idx,kk) @ (idx*2+kk)*512 + lane*8 u16
//   vS  tile (b*64+kt):  frag(kk,dt)  @ (kk*4+dt)*512 + lane*8 u16
__global__ __launch_bounds__(256) void HeadV1_proj(
    const float* __restrict__ x, const float* __restrict__ Wk,
    const float* __restrict__ Wq, const float* __restrict__ Wv,
    u16* __restrict__ qS, u16* __restrict__ kS, u16* __restrict__ vS)
{
  __shared__ u16 xl[64][72];      // 9216 B
  __shared__ u16 Wl[3][64][72];   // 27648 B
  __shared__ u16 ylds[64][72];    // 9216 B  (total 46 KB)

  const int t = threadIdx.x;
  const int w = t >> 6, lane = t & 63, l15 = lane & 15, quad = lane >> 4;
  const int r0 = blockIdx.x * 64;
  const int b  = r0 >> 12;
  const int kt = (r0 & 4095) >> 6;
  const long tilebase = ((long)(b * 64 + kt)) * 4096;

  { // coalesced fp32 staging with one-time bf16 conversion
    const float* srcs[4] = {x + (long)r0 * 64, Wk, Wq, Wv};
    u16* dstl[4] = {&xl[0][0], &Wl[0][0][0], &Wl[1][0][0], &Wl[2][0][0]};
    #pragma unroll
    for (int mm = 0; mm < 4; mm++) {
      const float* s = srcs[mm];
      u16* d = dstl[mm];
      #pragma unroll
      for (int i = 0; i < 4; i++) {
        const int f4 = i * 256 + t;        // 1024 float4 per 64x64 tile
        const int row = f4 >> 4, c4 = f4 & 15;
        float4 v = ((const float4*)(s + row * 64))[c4];
        uint2 pk;
        pk.x = pk2(v.x, v.y);
        pk.y = pk2(v.z, v.w);
        *(uint2*)(d + row * 72 + c4 * 4) = pk;
      }
    }
  }
  __syncthreads();

  bf16x8_t xf[2];
  #pragma unroll
  for (int kh = 0; kh < 2; kh++)
    xf[kh] = ld16(&xl[w * 16 + l15][kh * 32 + quad * 8]);

  u16* dsts[3];
  dsts[0] = kS + tilebase; dsts[1] = qS + tilebase; dsts[2] = vS + tilebase;

  #pragma unroll
  for (int m = 0; m < 3; m++) {
    float vals[4][4];
    #pragma unroll
    for (int g = 0; g < 4; g++) {
      f32x4_t acc = {0.f, 0.f, 0.f, 0.f};
      #pragma unroll
      for (int kh = 0; kh < 2; kh++) {
        bf16x8_t wf = ld16(&Wl[m][g * 16 + l15][kh * 32 + quad * 8]);
        acc = mfma16(xf[kh], wf, acc);
      }
      #pragma unroll
      for (int r = 0; r < 4; r++)
        vals[g][r] = (m == 1) ? acc[r] * QSCALE : acc[r];
    }
    #pragma unroll
    for (int g = 0; g < 4; g++)
      #pragma unroll
      for (int r = 0; r < 4; r++)
        ylds[w * 16 + quad * 4 + r][g * 16 + l15] = f2bf(vals[g][r]);
    __syncthreads();
    if (m < 2) {
      #pragma unroll
      for (int kk = 0; kk < 2; kk++) {
        bf16x8_t f = ld16(&ylds[w * 16 + l15][kk * 32 + quad * 8]);
        *(int4*)(dsts[m] + (w * 2 + kk) * 512 + lane * 8) = __builtin_bit_cast(int4, f);
      }
    } else {
      #pragma unroll
      for (int kk = 0; kk < 2; kk++) {
        u16 tmp[8];
        #pragma unroll
        for (int j = 0; j < 8; j++)
          tmp[j] = ylds[kk * 32 + quad * 8 + j][w * 16 + l15];
        *(int4*)(dsts[2] + (kk * 4 + w) * 512 + lane * 8) = *(const int4*)tmp;
      }
    }
    __syncthreads();
  }
}

// ---------------- flash v14: v10 + XCD-locked batches (K/V of one b resident in one L2) ----------------
// MI355X dispatches consecutive blockIdx round-robin across 8 XCDs (xcd = bid & 7). Decode
//   b = (bid & 7) >> 1   -> all blocks touching batch b run on XCD pair {2b, 2b+1};
//   i = ((bid >> 3) << 1) | (bid & 1)
// so each XCD's L2 working set = K+V of ONE batch = 4 MB (fits), instead of all 4 batches (16 MB
// thrash -> every K/V re-read served by Infinity Cache at ~900cy). Bijective over 256 blocks.
// Everything else identical to v10 (R2 verified, 84.6 us).
__global__ __launch_bounds__(1024, 4) void HeadV1_flash(
    const u16* __restrict__ qS, const u16* __restrict__ kS,
    const u16* __restrict__ vS, float* __restrict__ outg)
{
  __shared__ __align__(16) char smem[53248];
  u16  (*pT)[32][36]   = (u16 (*)[32][36])smem;                  // [16][32][36] u16 = 36864 B (main loop)
  float (*chk)[16][33] = (float (*)[16][33])smem;                // [16][16][33] f32 = 33792 B (overlays pT)
  float (*stg)[32][68] = (float (*)[32][68])(smem + 33792);      // [2][32][68]  f32 = 17408 B
  float (*lst)[32]     = (float (*)[32])(smem + 33792 + 17408);  // [16][32]     f32 =  2048 B

  const int t    = threadIdx.x;
  const int w    = t >> 6;        // 0..15
  const int lane = t & 63;
  const int l15  = lane & 15;
  const int quad = lane >> 4;

  const int xcd = blockIdx.x & 7;
  const int b   = xcd >> 1;                              // batch locked to XCD pair
  const int i   = ((blockIdx.x >> 3) << 1) | (xcd & 1);  // 0..63
  const int j1 = i, j2 = 127 - i;
  const int nk1 = (j1 >> 1) + 1;
  const int nk2 = (j2 >> 1) + 1;       // nk1 + nk2 == 65
  int n1 = (16 * nk1 + 32) / 65;       // round(16*nk1/65)
  if (n1 < 1) n1 = 1;
  if (n1 > 15) n1 = 15;

  const bool grp2 = (w >= n1);
  const int j   = grp2 ? j2 : j1;
  const int nk  = grp2 ? nk2 : nk1;
  const int str = grp2 ? (16 - n1) : n1;
  const int off = grp2 ? (w - n1) : w;

  const int qt64 = j >> 1;
  const int ql0  = (j & 1) * 32;
  const int qr0  = j * 32;
  const long base = (long)b * Tt * Dd;

  union { u32 u4[4]; bf16x8_t v; } uo;
  uo.u4[0] = uo.u4[1] = uo.u4[2] = uo.u4[3] = 0x3F803F80u; // bf16 1.0 x8
  const bf16x8_t ones = uo.v;
  const f32x4_t zero4 = {0.f, 0.f, 0.f, 0.f};

  const u16* qtile = qS + ((long)(b * 64 + qt64)) * 4096 + lane * 8;
  bf16x8_t qfrag[2][2];
  #pragma unroll
  for (int ct = 0; ct < 2; ct++)
    #pragma unroll
    for (int kd = 0; kd < 2; kd++)
      qfrag[ct][kd] = ld16(qtile + ((ql0 / 16 + ct) * 2 + kd) * 512);

  f32x4_t O[4][2];   // [dt][ct]
  #pragma unroll
  for (int a = 0; a < 4; a++)
    #pragma unroll
    for (int c = 0; c < 2; c++)
      O[a][c] = zero4;
  f32x4_t Lc[2] = {zero4, zero4};

  for (int kt = off; kt < nk; kt += str) {
    const bool ismask = (kt == nk - 1);
    const int kv0 = kt * 64;
    const u16* ktile = kS + ((long)(b * 64 + kt)) * 4096 + lane * 8;
    const u16* vtile = vS + ((long)(b * 64 + kt)) * 4096 + lane * 8;

    #pragma unroll
    for (int kk = 0; kk < 2; kk++) {     // kv-half phase
      bf16x8_t vf[4];
      #pragma unroll
      for (int dt = 0; dt < 4; dt++)
        vf[dt] = ld16(vtile + (kk * 4 + dt) * 512);

      #pragma unroll
      for (int rtl = 0; rtl < 2; rtl++) {
        const int rt = kk * 2 + rtl;
        bf16x8_t kf0 = ld16(ktile + (rt * 2 + 0) * 512);
        bf16x8_t kf1 = ld16(ktile + (rt * 2 + 1) * 512);
        #pragma unroll
        for (int ct = 0; ct < 2; ct++) {
          f32x4_t acc = zero4;
          acc = mfma16(kf0, qfrag[ct][0], acc);
          acc = mfma16(kf1, qfrag[ct][1], acc);
          if (ismask) {
            const int kvl = kv0 + rt * 16 + quad * 4;
            const int qi  = qr0 + ct * 16 + l15;
            #pragma unroll
            for (int r = 0; r < 4; r++)
              if (kvl + r > qi) acc[r] = -1e30f;   // v_exp -> 0
          }
          const float p0 = __builtin_amdgcn_exp2f(acc[0]);
          const float p1 = __builtin_amdgcn_exp2f(acc[1]);
          const float p2 = __builtin_amdgcn_exp2f(acc[2]);
          const float p3 = __builtin_amdgcn_exp2f(acc[3]);
          uint2 pk;
          pk.x = pkt(p0, p1);
          pk.y = pkt(p2, p3);
          *(uint2*)&pT[w][ct * 16 + l15][rtl * 16 + quad * 4] = pk;
        }
      }
      #pragma unroll
      for (int ct = 0; ct < 2; ct++) {
        bf16x8_t pf = ld16(&pT[w][ct * 16 + l15][quad * 8]);
        #pragma unroll
        for (int dt = 0; dt < 4; dt++)
          O[dt][ct] = mfma16(vf[dt], pf, O[dt][ct]);
        Lc[ct] = mfma16(ones, pf, Lc[ct]);
      }
    }
  }

  // ---- 16-wave merge, per-j wave ranges [0,n1) / [n1,16) ----
  if (quad == 0) {
    #pragma unroll
    for (int ct = 0; ct < 2; ct++)
      lst[w][ct * 16 + l15] = Lc[ct][0];
  }
  __syncthreads();  // pT dead past here; chk/stg overlay it

  #pragma unroll
  for (int dt = 0; dt < 4; dt++) {
    #pragma unroll
    for (int ct = 0; ct < 2; ct++)
      #pragma unroll
      for (int r = 0; r < 4; r++)
        chk[w][quad * 4 + r][ct * 16 + l15] = O[dt][ct][r];
    __syncthreads();
    {
      const int jsel = t >> 9, tt = t & 511;
      const int d2 = tt >> 5, q = tt & 31;   // 512 threads = 16 d x 32 q per jsel
      const int lo = jsel ? n1 : 0, hi = jsel ? 16 : n1;
      float s = 0.f;
      for (int w2 = lo; w2 < hi; w2++) s += chk[w2][d2][q];
      stg[jsel][q][dt * 16 + d2] = s;
    }
    __syncthreads();
  }

  { // normalize + coalesced fp32 write: per jsel, 32 q x 64 d (512 thr x 16 B)
    const int jsel = t >> 9, tt = t & 511;
    const int q = tt >> 4, dg = tt & 15;
    const int lo = jsel ? n1 : 0, hi = jsel ? 16 : n1;
    float L = 0.f;
    for (int w2 = lo; w2 < hi; w2++) L += lst[w2][q];
    const float invL = 1.0f / L;
    const int jj = jsel ? j2 : j1;
    float4 v = *(const float4*)&stg[jsel][q][dg * 4];
    v.x *= invL; v.y *= invL; v.z *= invL; v.w *= invL;
    *(float4*)(outg + base + (long)(jj * 32 + q) * 64 + dg * 4) = v;
  }
}

extern "C" void kernel_launch(void* const* d_in, const int* in_sizes, int n_in,
                              void* d_out, int out_size, void* d_ws, size_t ws_size,
                              hipStream_t stream) {
  (void)in_sizes; (void)n_in; (void)out_size; (void)ws_size;
  const float* x  = (const float*)d_in[0];
  const float* Wk = (const float*)d_in[1];
  const float* Wq = (const float*)d_in[2];
  const float* Wv = (const float*)d_in[3];
  float* out = (float*)d_out;
  // workspace: qS 2MB | kS 2MB | vS 2MB (all in MFMA-fragment order)
  u16* qw  = (u16*)d_ws;
  u16* kw  = qw + (size_t)Bb * Tt * Dd;
  u16* vw  = kw + (size_t)Bb * Tt * Dd;

  HeadV1_proj<<<(Bb * Tt) / 64, 256, 0, stream>>>(x, Wk, Wq, Wv, qw, kw, vw);
  HeadV1_flash<<<256, 1024, 0, stream>>>(qw, kw, vw, out);
}

// Round 8
// 83.129 us; speedup vs baseline: 1.5727x; 1.0078x over previous
//
#include <hip/hip_runtime.h>
#include <hip/hip_bf16.h>

typedef unsigned short u16;
typedef unsigned int u32;
typedef __bf16 bf16x8_t __attribute__((ext_vector_type(8)));
typedef float f32x4_t __attribute__((ext_vector_type(4)));
typedef float f32x16 __attribute__((ext_vector_type(16)));

constexpr int Bb = 4;
constexpr int Tt = 4096;
constexpr int Dd = 64;
constexpr float QSCALE = 0.18033688011112042f; // 0.125 * log2(e), folded into q

__device__ __forceinline__ u16 f2bf(float f) { // RNE
  unsigned int u = __builtin_bit_cast(unsigned int, f);
  return (u16)((u + 0x7fffu + ((u >> 16) & 1u)) >> 16);
}
__device__ __forceinline__ u32 pk2(float a, float b) { // RNE pack
  return (u32)f2bf(a) | ((u32)f2bf(b) << 16);
}
__device__ __forceinline__ u32 pkt(float a, float b) { // truncation pack (3 inst)
  const u32 ua = __builtin_bit_cast(u32, a);
  const u32 ub = __builtin_bit_cast(u32, b);
  return (ua >> 16) | (ub & 0xFFFF0000u);
}
__device__ __forceinline__ bf16x8_t ld16(const u16* p) {
  int4 v = *(const int4*)p;
  return __builtin_bit_cast(bf16x8_t, v);
}
__device__ __forceinline__ f32x4_t mfma16(bf16x8_t a, bf16x8_t b, f32x4_t c) {
  return __builtin_amdgcn_mfma_f32_16x16x32_bf16(a, b, c, 0, 0, 0);
}
__device__ __forceinline__ f32x16 mfma32(bf16x8_t a, bf16x8_t b, f32x16 c) {
  return __builtin_amdgcn_mfma_f32_32x32x16_bf16(a, b, c, 0, 0, 0);
}

// ---------------- proj v4 (R17, verified): LDS-staged x and W, fragment-order outputs ----------------
//   qS/kS tile (b*64+t): frag(idx,kk) @ (idx*2+kk)*512 + lane*8 u16
//     element semantics: X[idx*16 + (lane&15)][kk*32 + (lane>>4)*8 + j]
//   vS  tile (b*64+kt):  frag(kk,dt)  @ (kk*4+dt)*512 + lane*8 u16
//     element semantics: V^T[dt*16 + (lane&15)][kk*32 + (lane>>4)*8 + j]
__global__ __launch_bounds__(256) void HeadV1_proj(
    const float* __restrict__ x, const float* __restrict__ Wk,
    const float* __restrict__ Wq, const float* __restrict__ Wv,
    u16* __restrict__ qS, u16* __restrict__ kS, u16* __restrict__ vS)
{
  __shared__ u16 xl[64][72];      // 9216 B
  __shared__ u16 Wl[3][64][72];   // 27648 B
  __shared__ u16 ylds[64][72];    // 9216 B  (total 46 KB)

  const int t = threadIdx.x;
  const int w = t >> 6, lane = t & 63, l15 = lane & 15, quad = lane >> 4;
  const int r0 = blockIdx.x * 64;
  const int b  = r0 >> 12;
  const int kt = (r0 & 4095) >> 6;
  const long tilebase = ((long)(b * 64 + kt)) * 4096;

  { // coalesced fp32 staging with one-time bf16 conversion
    const float* srcs[4] = {x + (long)r0 * 64, Wk, Wq, Wv};
    u16* dstl[4] = {&xl[0][0], &Wl[0][0][0], &Wl[1][0][0], &Wl[2][0][0]};
    #pragma unroll
    for (int mm = 0; mm < 4; mm++) {
      const float* s = srcs[mm];
      u16* d = dstl[mm];
      #pragma unroll
      for (int i = 0; i < 4; i++) {
        const int f4 = i * 256 + t;        // 1024 float4 per 64x64 tile
        const int row = f4 >> 4, c4 = f4 & 15;
        float4 v = ((const float4*)(s + row * 64))[c4];
        uint2 pk;
        pk.x = pk2(v.x, v.y);
        pk.y = pk2(v.z, v.w);
        *(uint2*)(d + row * 72 + c4 * 4) = pk;
      }
    }
  }
  __syncthreads();

  bf16x8_t xf[2];
  #pragma unroll
  for (int kh = 0; kh < 2; kh++)
    xf[kh] = ld16(&xl[w * 16 + l15][kh * 32 + quad * 8]);

  u16* dsts[3];
  dsts[0] = kS + tilebase; dsts[1] = qS + tilebase; dsts[2] = vS + tilebase;

  #pragma unroll
  for (int m = 0; m < 3; m++) {
    float vals[4][4];
    #pragma unroll
    for (int g = 0; g < 4; g++) {
      f32x4_t acc = {0.f, 0.f, 0.f, 0.f};
      #pragma unroll
      for (int kh = 0; kh < 2; kh++) {
        bf16x8_t wf = ld16(&Wl[m][g * 16 + l15][kh * 32 + quad * 8]);
        acc = mfma16(xf[kh], wf, acc);
      }
      #pragma unroll
      for (int r = 0; r < 4; r++)
        vals[g][r] = (m == 1) ? acc[r] * QSCALE : acc[r];
    }
    #pragma unroll
    for (int g = 0; g < 4; g++)
      #pragma unroll
      for (int r = 0; r < 4; r++)
        ylds[w * 16 + quad * 4 + r][g * 16 + l15] = f2bf(vals[g][r]);
    __syncthreads();
    if (m < 2) {
      #pragma unroll
      for (int kk = 0; kk < 2; kk++) {
        bf16x8_t f = ld16(&ylds[w * 16 + l15][kk * 32 + quad * 8]);
        *(int4*)(dsts[m] + (w * 2 + kk) * 512 + lane * 8) = __builtin_bit_cast(int4, f);
      }
    } else {
      #pragma unroll
      for (int kk = 0; kk < 2; kk++) {
        u16 tmp[8];
        #pragma unroll
        for (int j = 0; j < 8; j++)
          tmp[j] = ylds[kk * 32 + quad * 8 + j][w * 16 + l15];
        *(int4*)(dsts[2] + (kk * 4 + w) * 512 + lane * 8) = *(const int4*)tmp;
      }
    }
    __syncthreads();
  }
}

// ---------------- flash v15: 32x32 MFMA, in-register softmax (zero LDS in main loop) ----------------
// S^T = K*Q^T via mfma_32x32x16: lane holds P[kv=(r&3)+8*(r>>2)+4*lhb][q=lane&31] -- q column
// matches the PV B-operand layout, so the pT LDS round-trip is replaced by 8 pkt + 4 shfl_xor(32)
// per kv-32 (partner lane holds the other kv-slots). PV: O^T[dh] += mfma32(Vfrag, Pfrag).
// Kills both lgkmcnt legs + ds traffic per phase; 8 wide MFMAs/visit instead of 36 narrow.
// Wave split / pair balancing / XCD-locked decode identical to v14.
__global__ __launch_bounds__(1024, 4) void HeadV1_flash(
    const u16* __restrict__ qS, const u16* __restrict__ kS,
    const u16* __restrict__ vS, float* __restrict__ outg)
{
  __shared__ __align__(16) char smem[55296];
  float (*chk)[16][33]  = (float (*)[16][33])smem;              // [16][16][33] f32 = 33792 B
  float (*stg)[32][68]  = (float (*)[32][68])(smem + 33792);    // [2][32][68]  f32 = 17408 B
  float (*lst)[2][32]   = (float (*)[2][32])(smem + 51200);     // [16][2][32]  f32 =  4096 B

  const int t    = threadIdx.x;
  const int w    = t >> 6;        // 0..15
  const int lane = t & 63;
  const int l15  = lane & 15;
  const int lhb  = lane >> 5;     // half-of-wave
  const int l4   = (lane >> 4) & 1;
  const int q31  = lane & 31;

  const int xcd = blockIdx.x & 7;
  const int b   = xcd >> 1;                              // batch locked to XCD pair (R7)
  const int i   = ((blockIdx.x >> 3) << 1) | (xcd & 1);  // 0..63
  const int j1 = i, j2 = 127 - i;
  const int nk1 = (j1 >> 1) + 1;
  const int nk2 = (j2 >> 1) + 1;       // nk1 + nk2 == 65
  int n1 = (16 * nk1 + 32) / 65;       // round(16*nk1/65)
  if (n1 < 1) n1 = 1;
  if (n1 > 15) n1 = 15;

  const bool grp2 = (w >= n1);
  const int j   = grp2 ? j2 : j1;
  const int nk  = grp2 ? nk2 : nk1;
  const int str = grp2 ? (16 - n1) : n1;
  const int off = grp2 ? (w - n1) : w;

  const int qt64 = j >> 1;
  const int ql0  = (j & 1) * 32;
  const int qr0  = j * 32;
  const long base = (long)b * Tt * Dd;

  // Q fragments: B-operand of 32x32x16, B[k=d][col=q]: lane -> Q[ql0+q31][dsl*16 + lhb*8 + j]
  const u16* qt_ = qS + ((long)(b * 64 + qt64)) * 4096;
  bf16x8_t qfrag[4];
  #pragma unroll
  for (int dsl = 0; dsl < 4; dsl++)
    qfrag[dsl] = ld16(qt_ + (((ql0 >> 4) + l4) * 2 + (dsl >> 1)) * 512
                          + (((dsl * 2 + lhb) & 3) * 16 + l15) * 8);

  f32x16 O0 = {0.f,0.f,0.f,0.f,0.f,0.f,0.f,0.f,0.f,0.f,0.f,0.f,0.f,0.f,0.f,0.f};
  f32x16 O1 = O0;
  float Lp = 0.f;

  const u16* kb = kS + ((long)(b * 64)) * 4096;
  const u16* vb = vS + ((long)(b * 64)) * 4096;

  for (int kt = off; kt < nk; kt += str) {
    const bool ismask = (kt == nk - 1);
    const u16* ktile = kb + (long)kt * 4096;
    const u16* vtile = vb + (long)kt * 4096;
    // even-j diagonal tiles: upper kv-32 fully masked -> skip entirely
    const int nh = (ismask && !(j & 1)) ? 1 : 2;

    for (int h2 = 0; h2 < nh; h2++) {
      // K fragments: A[row=kv=h2*32+(lane&31)][k=d slice]
      bf16x8_t kf[4];
      #pragma unroll
      for (int dsl = 0; dsl < 4; dsl++)
        kf[dsl] = ld16(ktile + ((h2 * 2 + l4) * 2 + (dsl >> 1)) * 512
                             + (((dsl * 2 + lhb) & 3) * 16 + l15) * 8);
      // V fragments: A[row=d=dh*32+(lane&31)][k=kv slice ksl*16+lhb*8]
      bf16x8_t vf[2][2];
      #pragma unroll
      for (int ksl = 0; ksl < 2; ksl++)
        #pragma unroll
        for (int dh = 0; dh < 2; dh++)
          vf[ksl][dh] = ld16(vtile + (h2 * 4 + dh * 2 + l4) * 512
                                   + ((ksl * 2 + lhb) * 16 + l15) * 8);

      f32x16 S = {0.f,0.f,0.f,0.f,0.f,0.f,0.f,0.f,0.f,0.f,0.f,0.f,0.f,0.f,0.f,0.f};
      #pragma unroll
      for (int dsl = 0; dsl < 4; dsl++)
        S = mfma32(kf[dsl], qfrag[dsl], S);

      if (ismask && h2 == (j & 1)) {   // diagonal kv-32 only
        const int kvb = kt * 64 + h2 * 32 + 4 * lhb;
        const int qi  = qr0 + q31;
        #pragma unroll
        for (int r = 0; r < 16; r++) {
          const int kvg = kvb + (r & 3) + 8 * (r >> 2);
          if (kvg > qi) S[r] = -1e30f;   // exp2 -> 0
        }
      }

      float p[16];
      #pragma unroll
      for (int r = 0; r < 16; r++) p[r] = __builtin_amdgcn_exp2f(S[r]);
      #pragma unroll
      for (int r = 0; r < 16; r++) {   // L sums EXACTLY the truncated values PV consumes
        const u32 u = __builtin_bit_cast(u32, p[r]) & 0xFFFF0000u;
        Lp += __builtin_bit_cast(float, u);
      }

      #pragma unroll
      for (int ksl = 0; ksl < 2; ksl++) {
        const u32 a0 = pkt(p[8 * ksl + 0], p[8 * ksl + 1]);
        const u32 a1 = pkt(p[8 * ksl + 2], p[8 * ksl + 3]);
        const u32 a2 = pkt(p[8 * ksl + 4], p[8 * ksl + 5]);
        const u32 a3 = pkt(p[8 * ksl + 6], p[8 * ksl + 7]);
        // partner exchange: lo needs hi's a0,a1 (words 2,3); hi needs lo's a2,a3 (words 0,1)
        const u32 x02 = (u32)__shfl_xor((int)(lhb ? a0 : a2), 32);
        const u32 x13 = (u32)__shfl_xor((int)(lhb ? a1 : a3), 32);
        uint4 bw;
        bw.x = lhb ? x02 : a0;
        bw.y = lhb ? x13 : a1;
        bw.z = lhb ? a2 : x02;
        bw.w = lhb ? a3 : x13;
        const bf16x8_t Bf = __builtin_bit_cast(bf16x8_t, bw);
        __builtin_amdgcn_s_setprio(1);
        O0 = mfma32(vf[ksl][0], Bf, O0);
        O1 = mfma32(vf[ksl][1], Bf, O1);
        __builtin_amdgcn_s_setprio(0);
      }
    }
  }

  // ---- 16-wave merge, per-j wave ranges [0,n1) / [n1,16) ----
  lst[w][lhb][q31] = Lp;   // 64 lanes -> 64 distinct slots
  __syncthreads();

  #pragma unroll
  for (int rr = 0; rr < 4; rr++) {   // d_global = rr*16 + dloc
    #pragma unroll
    for (int rs = 0; rs < 8; rs++) {
      const int dloc = (rs & 3) + 8 * (rs >> 2) + 4 * lhb;
      const float val = (rr >> 1) ? ((rr & 1) ? O1[8 + rs] : O1[rs])
                                  : ((rr & 1) ? O0[8 + rs] : O0[rs]);
      chk[w][dloc][q31] = val;
    }
    __syncthreads();
    {
      const int jsel = t >> 9, tt = t & 511;
      const int d2 = tt >> 5, q = tt & 31;   // 512 threads = 16 d x 32 q per jsel
      const int lo = jsel ? n1 : 0, hi = jsel ? 16 : n1;
      float s = 0.f;
      for (int w2 = lo; w2 < hi; w2++) s += chk[w2][d2][q];
      stg[jsel][q][rr * 16 + d2] = s;
    }
    __syncthreads();
  }

  { // normalize + coalesced fp32 write: per jsel, 32 q x 64 d (512 thr x 16 B)
    const int jsel = t >> 9, tt = t & 511;
    const int q = tt >> 4, dg = tt & 15;
    const int lo = jsel ? n1 : 0, hi = jsel ? 16 : n1;
    float L = 0.f;
    for (int w2 = lo; w2 < hi; w2++) L += lst[w2][0][q] + lst[w2][1][q];
    const float invL = 1.0f / L;
    const int jj = jsel ? j2 : j1;
    float4 v = *(const float4*)&stg[jsel][q][dg * 4];
    v.x *= invL; v.y *= invL; v.z *= invL; v.w *= invL;
    *(float4*)(outg + base + (long)(jj * 32 + q) * 64 + dg * 4) = v;
  }
}

extern "C" void kernel_launch(void* const* d_in, const int* in_sizes, int n_in,
                              void* d_out, int out_size, void* d_ws, size_t ws_size,
                              hipStream_t stream) {
  (void)in_sizes; (void)n_in; (void)out_size; (void)ws_size;
  const float* x  = (const float*)d_in[0];
  const float* Wk = (const float*)d_in[1];
  const float* Wq = (const float*)d_in[2];
  const float* Wv = (const float*)d_in[3];
  float* out = (float*)d_out;
  // workspace: qS 2MB | kS 2MB | vS 2MB (all in MFMA-fragment order)
  u16* qw  = (u16*)d_ws;
  u16* kw  = qw + (size_t)Bb * Tt * Dd;
  u16* vw  = kw + (size_t)Bb * Tt * Dd;

  HeadV1_proj<<<(Bb * Tt) / 64, 256, 0, stream>>>(x, Wk, Wq, Wv, qw, kw, vw);
  HeadV1_flash<<<256, 1024, 0, stream>>>(qw, kw, vw, out);
}